// Round 6
// baseline (179.331 us; speedup 1.0000x reference)
//
#include <hip/hip_runtime.h>

#define BINS 4096            // 64 * 64
#define HIST_BLOCKS 1024
#define HIST_THREADS 512
#define PAIRS 8              // 8 (p,c) int4 pairs per thread = 16 dwordx4 in flight

typedef int intx4 __attribute__((ext_vector_type(4)));

// out[i] = transitions_in[i] for i < bins; out[bins] = total_in + n_events
__global__ void topo_init_kernel(const float* __restrict__ transitions,
                                 const float* __restrict__ total,
                                 float* __restrict__ out,
                                 float n_events_f, int bins) {
    int i = blockIdx.x * blockDim.x + threadIdx.x;
    if (i < bins) out[i] = transitions[i];
    if (i == 0) out[bins] = total[0] + n_events_f;
}

#define CONS(Pk, Ck)                                    \
    atomicAdd(&h[(Pk.x << 6) | Ck.x], 1u);              \
    atomicAdd(&h[(Pk.y << 6) | Ck.y], 1u);              \
    atomicAdd(&h[(Pk.z << 6) | Ck.z], 1u);              \
    atomicAdd(&h[(Pk.w << 6) | Ck.w], 1u)

#define WAITPAIR(N, Pk, Ck)                             \
    asm volatile("s_waitcnt vmcnt(" #N ")"              \
                 : "+v"(Pk), "+v"(Ck)::"memory")

// 16 global_load_dwordx4 issued in one asm block; "=&v" early-clobber is
// REQUIRED (R4 crash: outputs aliased onto still-live address inputs).
#define LOAD16_ASM(P0,C0,P1,C1,P2,C2,P3,C3,P4,C4,P5,C5,P6,C6,P7,C7,          \
                   o0,o1,o2,o3,o4,o5,o6,o7,pb,cb)                            \
    asm volatile(                                                            \
        "global_load_dwordx4 %[rP0], %[ro0], %[rpb]\n\t"                     \
        "global_load_dwordx4 %[rC0], %[ro0], %[rcb]\n\t"                     \
        "global_load_dwordx4 %[rP1], %[ro1], %[rpb]\n\t"                     \
        "global_load_dwordx4 %[rC1], %[ro1], %[rcb]\n\t"                     \
        "global_load_dwordx4 %[rP2], %[ro2], %[rpb]\n\t"                     \
        "global_load_dwordx4 %[rC2], %[ro2], %[rcb]\n\t"                     \
        "global_load_dwordx4 %[rP3], %[ro3], %[rpb]\n\t"                     \
        "global_load_dwordx4 %[rC3], %[ro3], %[rcb]\n\t"                     \
        "global_load_dwordx4 %[rP4], %[ro4], %[rpb]\n\t"                     \
        "global_load_dwordx4 %[rC4], %[ro4], %[rcb]\n\t"                     \
        "global_load_dwordx4 %[rP5], %[ro5], %[rpb]\n\t"                     \
        "global_load_dwordx4 %[rC5], %[ro5], %[rcb]\n\t"                     \
        "global_load_dwordx4 %[rP6], %[ro6], %[rpb]\n\t"                     \
        "global_load_dwordx4 %[rC6], %[ro6], %[rcb]\n\t"                     \
        "global_load_dwordx4 %[rP7], %[ro7], %[rpb]\n\t"                     \
        "global_load_dwordx4 %[rC7], %[ro7], %[rcb]"                         \
        : [rP0] "=&v"(P0), [rC0] "=&v"(C0), [rP1] "=&v"(P1), [rC1] "=&v"(C1),\
          [rP2] "=&v"(P2), [rC2] "=&v"(C2), [rP3] "=&v"(P3), [rC3] "=&v"(C3),\
          [rP4] "=&v"(P4), [rC4] "=&v"(C4), [rP5] "=&v"(P5), [rC5] "=&v"(C5),\
          [rP6] "=&v"(P6), [rC6] "=&v"(C6), [rP7] "=&v"(P7), [rC7] "=&v"(C7) \
        : [ro0] "v"(o0), [ro1] "v"(o1), [ro2] "v"(o2), [ro3] "v"(o3),        \
          [ro4] "v"(o4), [ro5] "v"(o5), [ro6] "v"(o6), [ro7] "v"(o7),        \
          [rpb] "s"(pb), [rcb] "s"(cb)                                       \
        : "memory")

__global__ void __launch_bounds__(HIST_THREADS)
topo_hist_kernel(const int* __restrict__ prev,
                 const int* __restrict__ curr,
                 float* __restrict__ out, int n) {
    __shared__ unsigned int h[BINS];
    for (int i = threadIdx.x; i < BINS; i += HIST_THREADS) h[i] = 0u;
    __syncthreads();

    const int n4 = n >> 2;
    const int total_threads = gridDim.x * HIST_THREADS;
    const int tid = blockIdx.x * HIST_THREADS + threadIdx.x;

    if (n4 == total_threads * PAIRS && (n & 3) == 0) {
        const int base = blockIdx.x * (HIST_THREADS * PAIRS) + threadIdx.x;
        const unsigned st = HIST_THREADS * 16u;          // 8 KB between k's
        const unsigned o0 = (unsigned)base * 16u;
        const unsigned o1 = o0 + st,     o2 = o0 + 2 * st, o3 = o0 + 3 * st,
                       o4 = o0 + 4 * st, o5 = o0 + 5 * st, o6 = o0 + 6 * st,
                       o7 = o0 + 7 * st;

        intx4 P0, P1, P2, P3, P4, P5, P6, P7;
        intx4 C0, C1, C2, C3, C4, C5, C6, C7;
        LOAD16_ASM(P0,C0,P1,C1,P2,C2,P3,C3,P4,C4,P5,C5,P6,C6,P7,C7,
                   o0,o1,o2,o3,o4,o5,o6,o7,prev,curr);

        WAITPAIR(14, P0, C0); CONS(P0, C0);
        WAITPAIR(12, P1, C1); CONS(P1, C1);
        WAITPAIR(10, P2, C2); CONS(P2, C2);
        WAITPAIR(8,  P3, C3); CONS(P3, C3);
        WAITPAIR(6,  P4, C4); CONS(P4, C4);
        WAITPAIR(4,  P5, C5); CONS(P5, C5);
        WAITPAIR(2,  P6, C6); CONS(P6, C6);
        WAITPAIR(0,  P7, C7); CONS(P7, C7);
    } else {
        const int4* __restrict__ p4 = (const int4*)prev;
        const int4* __restrict__ c4 = (const int4*)curr;
        for (int i = tid; i < n4; i += total_threads) {
            int4 p = p4[i];
            int4 c = c4[i];
            atomicAdd(&h[(p.x << 6) | c.x], 1u);
            atomicAdd(&h[(p.y << 6) | c.y], 1u);
            atomicAdd(&h[(p.z << 6) | c.z], 1u);
            atomicAdd(&h[(p.w << 6) | c.w], 1u);
        }
        for (int t = (n4 << 2) + tid; t < n; t += total_threads) {
            atomicAdd(&h[(prev[t] << 6) | curr[t]], 1u);
        }
    }

    __syncthreads();
    for (int b = threadIdx.x; b < BINS; b += HIST_THREADS) {
        unsigned int c = h[b];
        if (c) atomicAdd(&out[b], (float)c);
    }
}

// ---------- DIAGNOSTIC A: pure load-path floor (no LDS, no atomics) ----------
__global__ void __launch_bounds__(HIST_THREADS)
ablate_loads_kernel(const int* __restrict__ prev,
                    const int* __restrict__ curr, int n) {
    const int base = blockIdx.x * (HIST_THREADS * PAIRS) + threadIdx.x;
    const unsigned st = HIST_THREADS * 16u;
    const unsigned o0 = (unsigned)base * 16u;
    const unsigned o1 = o0 + st,     o2 = o0 + 2 * st, o3 = o0 + 3 * st,
                   o4 = o0 + 4 * st, o5 = o0 + 5 * st, o6 = o0 + 6 * st,
                   o7 = o0 + 7 * st;
    intx4 P0, P1, P2, P3, P4, P5, P6, P7;
    intx4 C0, C1, C2, C3, C4, C5, C6, C7;
    LOAD16_ASM(P0,C0,P1,C1,P2,C2,P3,C3,P4,C4,P5,C5,P6,C6,P7,C7,
               o0,o1,o2,o3,o4,o5,o6,o7,prev,curr);
    // Drain + keep-alive (rule #17): values consumed by volatile asm, no DCE.
    asm volatile("s_waitcnt vmcnt(0)"
                 :: "v"(P0), "v"(C0), "v"(P1), "v"(C1),
                    "v"(P2), "v"(C2), "v"(P3), "v"(C3),
                    "v"(P4), "v"(C4), "v"(P5), "v"(C5),
                    "v"(P6), "v"(C6), "v"(P7), "v"(C7) : "memory");
}

// ---------- DIAGNOSTIC B: pure DS-atomic floor (no global loads) ----------
__global__ void __launch_bounds__(HIST_THREADS)
ablate_ds_kernel(int n) {
    __shared__ unsigned int h[BINS];
    for (int i = threadIdx.x; i < BINS; i += HIST_THREADS) h[i] = 0u;
    __syncthreads();
    const int tid = blockIdx.x * HIST_THREADS + threadIdx.x;
    // 32 synthetic atomics/thread, hashed bins (same count/distribution as real)
    unsigned x = (unsigned)tid * 2654435761u + 12345u;
#pragma unroll
    for (int j = 0; j < 32; ++j) {
        x = x * 1664525u + 1013904223u;          // LCG, cheap VALU
        atomicAdd(&h[(x >> 20) & (BINS - 1)], 1u);
    }
    __syncthreads();
    unsigned v = h[threadIdx.x & (BINS - 1)];
    asm volatile("" :: "v"(v));                   // keep-alive, no global write
}

extern "C" void kernel_launch(void* const* d_in, const int* in_sizes, int n_in,
                              void* d_out, int out_size, void* d_ws, size_t ws_size,
                              hipStream_t stream) {
    const int*   prev        = (const int*)d_in[0];
    const int*   curr        = (const int*)d_in[1];
    const float* transitions = (const float*)d_in[2];
    const float* total       = (const float*)d_in[3];
    float* out = (float*)d_out;

    const int n    = in_sizes[0];
    const int bins = in_sizes[2];   // 4096

    // 1) initialize output: copy transitions input, set total = total_in + n
    int init_blocks = (bins + 1 + 255) / 256;
    topo_init_kernel<<<init_blocks, 256, 0, stream>>>(transitions, total, out,
                                                      (float)n, bins);

    // 2) real histogram (R5 current-best, unchanged) — correctness path
    topo_hist_kernel<<<HIST_BLOCKS, HIST_THREADS, 0, stream>>>(prev, curr, out, n);

    // 3) DIAGNOSTIC-ONLY dispatches (outputs unused; removed next round).
    //    Only run in the exact-cover configuration they're built for.
    if (n == HIST_BLOCKS * HIST_THREADS * PAIRS * 4) {
        ablate_loads_kernel<<<HIST_BLOCKS, HIST_THREADS, 0, stream>>>(prev, curr, n);
        ablate_ds_kernel<<<HIST_BLOCKS, HIST_THREADS, 0, stream>>>(n);
    }
}

// Round 7
// 155.414 us; speedup vs baseline: 1.1539x; 1.1539x over previous
//
#include <hip/hip_runtime.h>

#define BINS 4096            // 64 * 64
#define HIST_BLOCKS 1024
#define HIST_THREADS 512
#define PAIRS 8              // 8 (p,c) int4 pairs per thread = 16 dwordx4 in flight

typedef int intx4 __attribute__((ext_vector_type(4)));

// out[i] = transitions_in[i] for i < bins; out[bins] = total_in + n_events
__global__ void topo_init_kernel(const float* __restrict__ transitions,
                                 const float* __restrict__ total,
                                 float* __restrict__ out,
                                 float n_events_f, int bins) {
    int i = blockIdx.x * blockDim.x + threadIdx.x;
    if (i < bins) out[i] = transitions[i];
    if (i == 0) out[bins] = total[0] + n_events_f;
}

#define CONS(Pk, Ck)                                    \
    atomicAdd(&h[(Pk.x << 6) | Ck.x], 1u);              \
    atomicAdd(&h[(Pk.y << 6) | Ck.y], 1u);              \
    atomicAdd(&h[(Pk.z << 6) | Ck.z], 1u);              \
    atomicAdd(&h[(Pk.w << 6) | Ck.w], 1u)

// 16 global_load_dwordx4 issued in one asm block; "=&v" early-clobber is
// REQUIRED (R4 crash: outputs aliased onto still-live address inputs).
#define LOAD16_ASM(P0,C0,P1,C1,P2,C2,P3,C3,P4,C4,P5,C5,P6,C6,P7,C7,          \
                   o0,o1,o2,o3,o4,o5,o6,o7,pb,cb)                            \
    asm volatile(                                                            \
        "global_load_dwordx4 %[rP0], %[ro0], %[rpb]\n\t"                     \
        "global_load_dwordx4 %[rC0], %[ro0], %[rcb]\n\t"                     \
        "global_load_dwordx4 %[rP1], %[ro1], %[rpb]\n\t"                     \
        "global_load_dwordx4 %[rC1], %[ro1], %[rcb]\n\t"                     \
        "global_load_dwordx4 %[rP2], %[ro2], %[rpb]\n\t"                     \
        "global_load_dwordx4 %[rC2], %[ro2], %[rcb]\n\t"                     \
        "global_load_dwordx4 %[rP3], %[ro3], %[rpb]\n\t"                     \
        "global_load_dwordx4 %[rC3], %[ro3], %[rcb]\n\t"                     \
        "global_load_dwordx4 %[rP4], %[ro4], %[rpb]\n\t"                     \
        "global_load_dwordx4 %[rC4], %[ro4], %[rcb]\n\t"                     \
        "global_load_dwordx4 %[rP5], %[ro5], %[rpb]\n\t"                     \
        "global_load_dwordx4 %[rC5], %[ro5], %[rcb]\n\t"                     \
        "global_load_dwordx4 %[rP6], %[ro6], %[rpb]\n\t"                     \
        "global_load_dwordx4 %[rC6], %[ro6], %[rcb]\n\t"                     \
        "global_load_dwordx4 %[rP7], %[ro7], %[rpb]\n\t"                     \
        "global_load_dwordx4 %[rC7], %[ro7], %[rcb]"                         \
        : [rP0] "=&v"(P0), [rC0] "=&v"(C0), [rP1] "=&v"(P1), [rC1] "=&v"(C1),\
          [rP2] "=&v"(P2), [rC2] "=&v"(C2), [rP3] "=&v"(P3), [rC3] "=&v"(C3),\
          [rP4] "=&v"(P4), [rC4] "=&v"(C4), [rP5] "=&v"(P5), [rC5] "=&v"(C5),\
          [rP6] "=&v"(P6), [rC6] "=&v"(C6), [rP7] "=&v"(P7), [rC7] "=&v"(C7) \
        : [ro0] "v"(o0), [ro1] "v"(o1), [ro2] "v"(o2), [ro3] "v"(o3),        \
          [ro4] "v"(o4), [ro5] "v"(o5), [ro6] "v"(o6), [ro7] "v"(o7),        \
          [rpb] "s"(pb), [rcb] "s"(cb)                                       \
        : "memory")

__global__ void __launch_bounds__(HIST_THREADS)
topo_hist_kernel(const int* __restrict__ prev,
                 const int* __restrict__ curr,
                 float* __restrict__ out, int n) {
    __shared__ unsigned int h[BINS];
    for (int i = threadIdx.x; i < BINS; i += HIST_THREADS) h[i] = 0u;
    __syncthreads();

    const int n4 = n >> 2;
    const int total_threads = gridDim.x * HIST_THREADS;
    const int tid = blockIdx.x * HIST_THREADS + threadIdx.x;

    if (n4 == total_threads * PAIRS && (n & 3) == 0) {
        // R6 decomposition: loads-only floor ~12-17us, DS-only floor ~4-8us,
        // but interleaved (R5 vmcnt cascade) = 45us -- the INTERACTION of
        // outstanding VMEM with dependent DS bursts is the cost. This round:
        // PHASE SEPARATION. (1) issue all 16 loads, (2) drain vmcnt(0) once --
        // all 32 events now in registers, ZERO VMEM outstanding, (3) barrier
        // aligns all 8 waves (4 identical blocks/CU align approximately),
        // (4) pure DS-atomic phase. Serialized phase floors: ~17+8us.
        const int base = blockIdx.x * (HIST_THREADS * PAIRS) + threadIdx.x;
        const unsigned st = HIST_THREADS * 16u;          // 8 KB between k's
        const unsigned o0 = (unsigned)base * 16u;
        const unsigned o1 = o0 + st,     o2 = o0 + 2 * st, o3 = o0 + 3 * st,
                       o4 = o0 + 4 * st, o5 = o0 + 5 * st, o6 = o0 + 6 * st,
                       o7 = o0 + 7 * st;

        intx4 P0, P1, P2, P3, P4, P5, P6, P7;
        intx4 C0, C1, C2, C3, C4, C5, C6, C7;
        LOAD16_ASM(P0,C0,P1,C1,P2,C2,P3,C3,P4,C4,P5,C5,P6,C6,P7,C7,
                   o0,o1,o2,o3,o4,o5,o6,o7,prev,curr);

        // Full drain; "+v" ties keep every consumer below the wait (rule #18).
        asm volatile("s_waitcnt vmcnt(0)"
                     : "+v"(P0), "+v"(C0), "+v"(P1), "+v"(C1),
                       "+v"(P2), "+v"(C2), "+v"(P3), "+v"(C3),
                       "+v"(P4), "+v"(C4), "+v"(P5), "+v"(C5),
                       "+v"(P6), "+v"(C6), "+v"(P7), "+v"(C7) :: "memory");
        __syncthreads();   // phase boundary: no VMEM in flight past this point

        CONS(P0, C0); CONS(P1, C1); CONS(P2, C2); CONS(P3, C3);
        CONS(P4, C4); CONS(P5, C5); CONS(P6, C6); CONS(P7, C7);
    } else {
        // Generic fallback: grid-stride (correct for any n).
        const int4* __restrict__ p4 = (const int4*)prev;
        const int4* __restrict__ c4 = (const int4*)curr;
        for (int i = tid; i < n4; i += total_threads) {
            int4 p = p4[i];
            int4 c = c4[i];
            atomicAdd(&h[(p.x << 6) | c.x], 1u);
            atomicAdd(&h[(p.y << 6) | c.y], 1u);
            atomicAdd(&h[(p.z << 6) | c.z], 1u);
            atomicAdd(&h[(p.w << 6) | c.w], 1u);
        }
        for (int t = (n4 << 2) + tid; t < n; t += total_threads) {
            atomicAdd(&h[(prev[t] << 6) | curr[t]], 1u);
        }
    }

    __syncthreads();
    // R1 finding: this contended float-atomic flush is FREE — keep simple form.
    for (int b = threadIdx.x; b < BINS; b += HIST_THREADS) {
        unsigned int c = h[b];
        if (c) atomicAdd(&out[b], (float)c);
    }
}

extern "C" void kernel_launch(void* const* d_in, const int* in_sizes, int n_in,
                              void* d_out, int out_size, void* d_ws, size_t ws_size,
                              hipStream_t stream) {
    const int*   prev        = (const int*)d_in[0];
    const int*   curr        = (const int*)d_in[1];
    const float* transitions = (const float*)d_in[2];
    const float* total       = (const float*)d_in[3];
    float* out = (float*)d_out;

    const int n    = in_sizes[0];
    const int bins = in_sizes[2];   // 4096

    // 1) initialize output: copy transitions input, set total = total_in + n
    int init_blocks = (bins + 1 + 255) / 256;
    topo_init_kernel<<<init_blocks, 256, 0, stream>>>(transitions, total, out,
                                                      (float)n, bins);

    // 2) per-block LDS histogram: load phase -> drain -> barrier -> DS phase
    topo_hist_kernel<<<HIST_BLOCKS, HIST_THREADS, 0, stream>>>(prev, curr, out, n);
}